// Round 7
// baseline (151.382 us; speedup 1.0000x reference)
//
#include <hip/hip_runtime.h>
#include <hip/hip_bf16.h>

#define BN 8
#define NN 2000
#define LL 128
#define EE 2048
#define DIN 258
#define KPAD 264
#define NROWS (BN*NN)
#define PENALTY_V 10.0f
#define NBINS 512
#define CANDCAP 384
#define SPLITK 16
#define ECHUNK (EE/SPLITK)   // 128
#define RPB 4                // rows (waves) per block

// ---------------- Kernel A1: partial Wc = W1@W2 over one K-slice ----------------
__global__ __launch_bounds__(256) void kA1(const float* __restrict__ W1,
                                           const float* __restrict__ b1,
                                           const float* __restrict__ W2,
                                           float* __restrict__ part) {
    __shared__ float As2[8][64];
    const int t = threadIdx.x;
    const int j = t & 127;
    const int half = t >> 7;              // 0 or 1
    const int rg = blockIdx.x >> 4;       // row group 0..32
    const int ks = blockIdx.x & 15;       // K slice 0..15
    const int k0 = rg * 8;
    const int ebase = ks * ECHUNK;
    float acc[4] = {0.f, 0.f, 0.f, 0.f};
    for (int ec = ebase; ec < ebase + ECHUNK; ec += 64) {
        #pragma unroll
        for (int q = 0; q < 2; ++q) {
            int linear = q * 256 + t;
            int r8 = linear >> 6;
            int e  = linear & 63;
            int k  = k0 + r8;
            float v;
            if (k < DIN)       v = W1[k * EE + ec + e];
            else if (k == DIN) v = b1[ec + e];
            else               v = 0.0f;
            As2[r8][e] = v;
        }
        __syncthreads();
        #pragma unroll 8
        for (int e = 0; e < 64; ++e) {
            float w = W2[(ec + e) * LL + j];
            #pragma unroll
            for (int rr = 0; rr < 4; ++rr)
                acc[rr] += As2[half * 4 + rr][e] * w;
        }
        __syncthreads();
    }
    #pragma unroll
    for (int rr = 0; rr < 4; ++rr) {
        int k = k0 + half * 4 + rr;       // < KPAD always (max 263)
        part[(size_t)ks * (KPAD * LL) + k * LL + j] = acc[rr];
    }
}

// ---------------- Kernel A2: reduce partials -> Wc, bc ----------------
__global__ __launch_bounds__(256) void kA2(const float* __restrict__ part,
                                           const float* __restrict__ b2,
                                           float* __restrict__ Wc,
                                           float* __restrict__ bc) {
    const int i = blockIdx.x * 256 + threadIdx.x;   // 0..KPAD*LL-1
    float s = 0.f;
    #pragma unroll
    for (int q = 0; q < SPLITK; ++q) s += part[(size_t)q * (KPAD * LL) + i];
    const int k = i >> 7;
    const int j = i & 127;
    if (k == DIN)      { bc[j] = s + b2[j]; Wc[i] = 0.f; }
    else if (k > DIN)  { Wc[i] = 0.f; }
    else               { Wc[i] = s; }
}

// ---- Kernel B: wave-per-row top-128. Register threshold-prune -> tiny LDS select. ----
// hist word layout: low16 = exclusive-prefix start (after scan), high16 = placed count.
__global__ __launch_bounds__(256) void kB(const float* __restrict__ dist,
                                          const float* __restrict__ theta,
                                          const float* __restrict__ f0,
                                          const float* __restrict__ f1,
                                          float* __restrict__ xin,
                                          int*   __restrict__ gidx) {
    __shared__ __align__(16) unsigned int hist_all[RPB][NBINS];          // 8 KB
    __shared__ __align__(16) unsigned long long cand_all[RPB][CANDCAP];  // 12 KB
    __shared__ __align__(16) float obuf_all[RPB][2 * LL];                // 4 KB
    __shared__ __align__(16) int   oidx_all[RPB][LL];                    // 2 KB
    __shared__ float sdm[RPB];

    const int t = threadIdx.x;
    const int lane = t & 63;
    const int w = t >> 6;
    const int row = blockIdx.x * RPB + w;

    unsigned int* hist = hist_all[w];
    unsigned long long* cand = cand_all[w];
    float* obuf = obuf_all[w];
    int* oidx = oidx_all[w];

    // init cand + hist (wave-local, no barrier needed anywhere in this kernel)
    {
        unsigned long long f1v = ~0ULL;
        #pragma unroll
        for (int q = 0; q < CANDCAP / 64; ++q) cand[lane + q * 64] = f1v;
        uint4 z4 = {0u, 0u, 0u, 0u};
        *(uint4*)&hist[lane * 8] = z4;
        *(uint4*)&hist[lane * 8 + 4] = z4;
    }

    // load row into registers: lane gets uint4 q*64+lane (q=0..7), elements (q*64+lane)*4+c
    unsigned int v[32];
    const int nv = (lane < 52) ? 32 : 28;    // 500 uint4 = 7*64 + 52
    {
        const uint4* drow4 = (const uint4*)(dist + (size_t)row * NN);
        #pragma unroll
        for (int q = 0; q < 8; ++q) {
            int qi = q * 64 + lane;
            if (qi < NN / 4) {
                uint4 a = drow4[qi];
                v[4 * q]     = a.x;
                v[4 * q + 1] = a.y;
                v[4 * q + 2] = a.z;
                v[4 * q + 3] = a.w;
            }
        }
    }

    // wave max (uint-bit max == float max for positive floats)
    unsigned int lmax = 0u;
    #pragma unroll
    for (int k = 0; k < 32; ++k) if (k < nv) lmax = max(lmax, v[k]);
    #pragma unroll
    for (int d = 1; d < 64; d <<= 1) lmax = max(lmax, (unsigned int)__shfl_xor((int)lmax, d));
    const float vmaxf = __uint_as_float(lmax);

    // threshold search in registers: find T with count(v<=T) in [LL, CANDCAP]
    float lo = 0.0f, hi = vmaxf;
    float T = vmaxf * 0.128f;
    unsigned int qm = 0u;
    bool ok = false;
    for (int it = 0; it < 32; ++it) {
        unsigned int m = 0u;
        #pragma unroll
        for (int k = 0; k < 32; ++k)
            if (k < nv && __uint_as_float(v[k]) <= T) m |= (1u << k);
        int c = __builtin_popcount(m);
        #pragma unroll
        for (int d = 1; d < 64; d <<= 1) c += __shfl_xor(c, d);
        qm = m;
        if (c >= LL && c <= CANDCAP) { ok = true; break; }
        if (c < LL) lo = T; else hi = T;
        float Ts = T * (256.0f / (float)(c > 16 ? c : 16));
        T = (Ts > lo && Ts < hi) ? Ts : 0.5f * (lo + hi);
    }
    if (!ok) {   // unreachable for continuous data; guaranteed-superset fallback
        T = hi;
        unsigned int m = 0u;
        #pragma unroll
        for (int k = 0; k < 32; ++k)
            if (k < nv && __uint_as_float(v[k]) <= T) m |= (1u << k);
        qm = m;
    }
    const float scale2 = (float)(NBINS - 1) / T;

    // histogram of candidates only (~250 lane-ops per wave total)
    {
        unsigned int m = qm;
        while (m) {
            int k = __builtin_ctz(m);
            m &= m - 1u;
            float f = __uint_as_float(v[k]);
            int b = (int)(f * scale2);
            b = b > NBINS - 1 ? NBINS - 1 : b;
            atomicAdd(&hist[b], 1u);
        }
    }

    // wave-synchronous exclusive scan: 8 consecutive bins per lane
    {
        uint4* h4 = (uint4*)&hist[lane * 8];
        uint4 a0 = h4[0], a1 = h4[1];
        unsigned int c[8] = {a0.x, a0.y, a0.z, a0.w, a1.x, a1.y, a1.z, a1.w};
        unsigned int loc[8], run = 0;
        #pragma unroll
        for (int k = 0; k < 8; ++k) { loc[k] = run; run += c[k]; }
        unsigned int inc = run;
        #pragma unroll
        for (int d = 1; d < 64; d <<= 1) {
            unsigned int o = (unsigned int)__shfl_up((int)inc, d);
            if (lane >= d) inc += o;
        }
        const unsigned int excl = inc - run;
        uint4 s0 = {excl + loc[0], excl + loc[1], excl + loc[2], excl + loc[3]};
        uint4 s1 = {excl + loc[4], excl + loc[5], excl + loc[6], excl + loc[7]};
        h4[0] = s0; h4[1] = s1;
    }

    // placement: slot = start + arrival order (one atomic per candidate)
    {
        unsigned int m = qm;
        while (m) {
            int k = __builtin_ctz(m);
            m &= m - 1u;
            unsigned int bits = v[k];
            float f = __uint_as_float(bits);
            int b = (int)(f * scale2);
            b = b > NBINS - 1 ? NBINS - 1 : b;
            unsigned int old = atomicAdd(&hist[b], 0x10000u);
            unsigned int slot = (old & 0xFFFFu) + (old >> 16);
            unsigned int idx = (unsigned int)((k >> 2) * 256 + lane * 4 + (k & 3));
            if (slot < (unsigned int)CANDCAP)
                cand[slot] = ((unsigned long long)bits << 32) | idx;
        }
    }

    // rank phase: read all slot keys, issue all theta gathers, then rank (tiny buckets)
    {
        unsigned long long key_s[CANDCAP / 64];
        float th_s[CANDCAP / 64];
        #pragma unroll
        for (int s = 0; s < CANDCAP / 64; ++s) key_s[s] = cand[lane + s * 64];
        #pragma unroll
        for (int s = 0; s < CANDCAP / 64; ++s)
            if (key_s[s] != ~0ULL)
                th_s[s] = theta[(size_t)row * NN + (unsigned int)key_s[s]];
        #pragma unroll
        for (int s = 0; s < CANDCAP / 64; ++s) {
            unsigned long long key = key_s[s];
            if (key != ~0ULL) {
                unsigned int bits = (unsigned int)(key >> 32);
                unsigned int idx  = (unsigned int)key;
                float f = __uint_as_float(bits);
                int b = (int)(f * scale2);
                b = b > NBINS - 1 ? NBINS - 1 : b;
                unsigned int word = hist[b];
                unsigned int start = word & 0xFFFFu;
                unsigned int end = start + (word >> 16);
                if (end > (unsigned int)CANDCAP) end = (unsigned int)CANDCAP;
                unsigned int r = start;
                for (unsigned int j = start; j < end; ++j) r += (cand[j] < key);
                if (r < (unsigned int)LL) {
                    obuf[r] = f;
                    obuf[LL + r] = th_s[s];
                    oidx[r] = (int)idx;
                    if (r == LL - 1) sdm[w] = f;
                }
            }
        }
    }

    // emit (coalesced): xrow[0..127]=dist/dmax, [128..255]=theta, [256..263]=features+pad
    {
        const float rdm = 1.0f / sdm[w];
        float* xrow = xin + (size_t)row * KPAD;
        float4 o = *(float4*)&obuf[lane * 4];
        if (lane < 32) { o.x *= rdm; o.y *= rdm; o.z *= rdm; o.w *= rdm; }
        *(float4*)&xrow[lane * 4] = o;
        if (lane == 0) {
            xrow[256] = f0[row];
            xrow[257] = f1[row];
            #pragma unroll
            for (int z = DIN; z < KPAD; ++z) xrow[z] = 0.0f;
        }
        int2 g = *(int2*)&oidx[lane * 2];
        *(int2*)&gidx[(size_t)row * LL + lane * 2] = g;
    }
}

// ---------------- Kernel C: val = xin @ Wc + bc - dn  (fp32 SGEMM, 128x128 tiles) ----------------
__global__ __launch_bounds__(256) void kC(const float* __restrict__ xin,
                                          const float* __restrict__ Wc,
                                          const float* __restrict__ bc,
                                          float* __restrict__ val) {
    __shared__ __align__(16) float As[8][132];
    __shared__ __align__(16) float Bs[8][128];
    const int t = threadIdx.x;
    const int tr = t >> 4, tc = t & 15;
    const int row0 = blockIdx.x * 128;
    float acc[8][8];
    #pragma unroll
    for (int i = 0; i < 8; ++i)
        #pragma unroll
        for (int j = 0; j < 8; ++j) acc[i][j] = 0.f;

    for (int kc = 0; kc < KPAD; kc += 8) {
        #pragma unroll
        for (int q = 0; q < 4; ++q) {
            int linear = q * 256 + t;
            int m = linear >> 3, k = linear & 7;
            As[k][m] = xin[(size_t)(row0 + m) * KPAD + kc + k];
        }
        #pragma unroll
        for (int q = 0; q < 4; ++q) {
            int linear = q * 256 + t;
            int k = linear >> 7, c = linear & 127;
            Bs[k][c] = Wc[(kc + k) * LL + c];
        }
        __syncthreads();
        #pragma unroll
        for (int k = 0; k < 8; ++k) {
            float a[8], b[8];
            *(float4*)&a[0] = *(const float4*)&As[k][tr * 8];
            *(float4*)&a[4] = *(const float4*)&As[k][tr * 8 + 4];
            *(float4*)&b[0] = *(const float4*)&Bs[k][tc * 8];
            *(float4*)&b[4] = *(const float4*)&Bs[k][tc * 8 + 4];
            #pragma unroll
            for (int i = 0; i < 8; ++i)
                #pragma unroll
                for (int j = 0; j < 8; ++j)
                    acc[i][j] += a[i] * b[j];
        }
        __syncthreads();
    }
    #pragma unroll
    for (int i = 0; i < 8; ++i) {
        int r = row0 + tr * 8 + i;
        #pragma unroll
        for (int j = 0; j < 8; ++j) {
            int c = tc * 8 + j;
            val[(size_t)r * LL + c] = acc[i][j] + bc[c] - xin[(size_t)r * KPAD + c];
        }
    }
}

// ---------------- Kernel D: fill PENALTY row + scatter, stream out ----------------
__global__ __launch_bounds__(256) void kD(const int* __restrict__ gidx,
                                          const float* __restrict__ val,
                                          float* __restrict__ out) {
    __shared__ __align__(16) float rowbuf[NN];
    const int t = threadIdx.x;
    const int row = blockIdx.x;
    for (int i = t; i < NN; i += 256) rowbuf[i] = PENALTY_V;
    __syncthreads();
    if (t < 128) rowbuf[gidx[(size_t)row * LL + t]] = val[(size_t)row * LL + t];
    __syncthreads();
    float4* out4 = (float4*)(out + (size_t)row * NN);
    const float4* rb4 = (const float4*)rowbuf;
    for (int q = t; q < NN / 4; q += 256) out4[q] = rb4[q];
}

extern "C" void kernel_launch(void* const* d_in, const int* in_sizes, int n_in,
                              void* d_out, int out_size, void* d_ws, size_t ws_size,
                              hipStream_t stream) {
    const float* theta = (const float*)d_in[0];
    const float* dist  = (const float*)d_in[1];
    const float* f0    = (const float*)d_in[2];
    const float* f1    = (const float*)d_in[3];
    const float* W1    = (const float*)d_in[4];
    const float* b1    = (const float*)d_in[5];
    const float* W2    = (const float*)d_in[6];
    const float* b2    = (const float*)d_in[7];
    float* out = (float*)d_out;

    char* ws = (char*)d_ws;
    float* Wc   = (float*)ws;                                   // KPAD*128*4 = 135168
    float* bc   = (float*)(ws + 135168);                        // 512
    float* xin  = (float*)(ws + 135680);                        // NROWS*KPAD*4 = 16896000
    int*   gidx = (int*)  (ws + 135680 + 16896000);             // NROWS*128*4 = 8192000
    float* val  = (float*)(ws + 135680 + 16896000 + 8192000);   // NROWS*128*4 = 8192000
    // part aliases val: kA1 writes it, kA2 consumes it, kC later overwrites val.
    float* part = val;                                          // SPLITK*KPAD*128*4 = 2162688 <= 8192000

    kA1<<<33 * SPLITK, 256, 0, stream>>>(W1, b1, W2, part);
    kA2<<<(KPAD * LL) / 256, 256, 0, stream>>>(part, b2, Wc, bc);
    kB<<<NROWS / RPB, 256, 0, stream>>>(dist, theta, f0, f1, xin, gidx);
    kC<<<NROWS / 128, 256, 0, stream>>>(xin, Wc, bc, val);
    kD<<<NROWS, 256, 0, stream>>>(gidx, val, out);
}

// Round 8
// 145.866 us; speedup vs baseline: 1.0378x; 1.0378x over previous
//
#include <hip/hip_runtime.h>
#include <hip/hip_bf16.h>

#define BN 8
#define NN 2000
#define LL 128
#define EE 2048
#define DIN 258
#define KPAD 264
#define NROWS (BN*NN)
#define PENALTY_V 10.0f
#define NBINS 256
#define CANDCAP 256
#define T0 0.092f
#define SPLITK 16
#define ECHUNK (EE/SPLITK)   // 128
#define RPB 4                // rows (waves) per block

// ---------------- Kernel A1: partial Wc = W1@W2 over one K-slice ----------------
__global__ __launch_bounds__(256) void kA1(const float* __restrict__ W1,
                                           const float* __restrict__ b1,
                                           const float* __restrict__ W2,
                                           float* __restrict__ part) {
    __shared__ float As2[8][64];
    const int t = threadIdx.x;
    const int j = t & 127;
    const int half = t >> 7;              // 0 or 1
    const int rg = blockIdx.x >> 4;       // row group 0..32
    const int ks = blockIdx.x & 15;       // K slice 0..15
    const int k0 = rg * 8;
    const int ebase = ks * ECHUNK;
    float acc[4] = {0.f, 0.f, 0.f, 0.f};
    for (int ec = ebase; ec < ebase + ECHUNK; ec += 64) {
        #pragma unroll
        for (int q = 0; q < 2; ++q) {
            int linear = q * 256 + t;
            int r8 = linear >> 6;
            int e  = linear & 63;
            int k  = k0 + r8;
            float v;
            if (k < DIN)       v = W1[k * EE + ec + e];
            else if (k == DIN) v = b1[ec + e];
            else               v = 0.0f;
            As2[r8][e] = v;
        }
        __syncthreads();
        #pragma unroll 8
        for (int e = 0; e < 64; ++e) {
            float w = W2[(ec + e) * LL + j];
            #pragma unroll
            for (int rr = 0; rr < 4; ++rr)
                acc[rr] += As2[half * 4 + rr][e] * w;
        }
        __syncthreads();
    }
    #pragma unroll
    for (int rr = 0; rr < 4; ++rr) {
        int k = k0 + half * 4 + rr;       // < KPAD always (max 263)
        part[(size_t)ks * (KPAD * LL) + k * LL + j] = acc[rr];
    }
}

// ---------------- Kernel A2: reduce partials -> Wc, bc ----------------
__global__ __launch_bounds__(256) void kA2(const float* __restrict__ part,
                                           const float* __restrict__ b2,
                                           float* __restrict__ Wc,
                                           float* __restrict__ bc) {
    const int i = blockIdx.x * 256 + threadIdx.x;   // 0..KPAD*LL-1
    float s = 0.f;
    #pragma unroll
    for (int q = 0; q < SPLITK; ++q) s += part[(size_t)q * (KPAD * LL) + i];
    const int k = i >> 7;
    const int j = i & 127;
    if (k == DIN)      { bc[j] = s + b2[j]; Wc[i] = 0.f; }
    else if (k > DIN)  { Wc[i] = 0.f; }
    else               { Wc[i] = s; }
}

// ---- Kernel B: wave-per-row top-128 with COMPILE-TIME threshold (cold exact fallback). ----
// hist word layout: low16 = exclusive-prefix start (after scan), high16 = placed count.
__global__ __launch_bounds__(256) void kB(const float* __restrict__ dist,
                                          const float* __restrict__ theta,
                                          const float* __restrict__ f0,
                                          const float* __restrict__ f1,
                                          float* __restrict__ xin,
                                          int*   __restrict__ gidx) {
    __shared__ __align__(16) unsigned int hist_all[RPB][NBINS];          // 4 KB
    __shared__ __align__(16) unsigned long long cand_all[RPB][CANDCAP];  // 8 KB
    __shared__ __align__(16) float obuf_all[RPB][2 * LL];                // 4 KB
    __shared__ __align__(16) int   oidx_all[RPB][LL];                    // 2 KB
    __shared__ float sdm[RPB];

    const int t = threadIdx.x;
    const int lane = t & 63;
    const int w = t >> 6;
    const int row = blockIdx.x * RPB + w;

    unsigned int* hist = hist_all[w];
    unsigned long long* cand = cand_all[w];
    float* obuf = obuf_all[w];
    int* oidx = oidx_all[w];

    // init hist + cand (wave-local; no barriers anywhere in this kernel)
    {
        uint4 z4 = {0u, 0u, 0u, 0u};
        *(uint4*)&hist[lane * 4] = z4;                 // 4 bins/lane covers 256
        unsigned long long f1v = ~0ULL;
        #pragma unroll
        for (int q = 0; q < CANDCAP / 64; ++q) cand[lane + q * 64] = f1v;
    }

    // load row into registers: lane owns uint4s q*64+lane (q=0..7)
    unsigned int v[32];
    const int nv = (lane < 52) ? 32 : 28;    // 500 uint4 = 7*64 + 52
    {
        const uint4* drow4 = (const uint4*)(dist + (size_t)row * NN);
        #pragma unroll
        for (int q = 0; q < 8; ++q) {
            int qi = q * 64 + lane;
            if (qi < NN / 4) {
                uint4 a = drow4[qi];
                v[4 * q]     = a.x;
                v[4 * q + 1] = a.y;
                v[4 * q + 2] = a.z;
                v[4 * q + 3] = a.w;
            }
        }
    }

    // fixed-threshold qualify mask + wave count (common path: NO max, NO search)
    float T = T0;
    unsigned int qm = 0u;
    #pragma unroll
    for (int k = 0; k < 32; ++k)
        if (k < nv && __uint_as_float(v[k]) <= T) qm |= (1u << k);
    int cnt = __builtin_popcount(qm);
    #pragma unroll
    for (int d = 1; d < 64; d <<= 1) cnt += __shfl_xor(cnt, d);

    if (cnt < LL || cnt > CANDCAP) {
        // ---- cold fallback: exact bisection to land count in [LL, CANDCAP] ----
        unsigned int lmax = 0u;
        #pragma unroll
        for (int k = 0; k < 32; ++k) if (k < nv) lmax = max(lmax, v[k]);
        #pragma unroll
        for (int d = 1; d < 64; d <<= 1) lmax = max(lmax, (unsigned int)__shfl_xor((int)lmax, d));
        float lo = 0.0f, hi = __uint_as_float(lmax);
        if (cnt < LL) lo = T; else hi = T;
        for (int it = 0; it < 32; ++it) {
            T = 0.5f * (lo + hi);
            unsigned int m = 0u;
            #pragma unroll
            for (int k = 0; k < 32; ++k)
                if (k < nv && __uint_as_float(v[k]) <= T) m |= (1u << k);
            int c = __builtin_popcount(m);
            #pragma unroll
            for (int d = 1; d < 64; d <<= 1) c += __shfl_xor(c, d);
            qm = m;
            if (c >= LL && c <= CANDCAP) break;
            if (c < LL) lo = T; else hi = T;
        }
    }
    const float scale2 = (float)(NBINS - 1) / T;

    // histogram of candidates (static predicated loop — no dynamic v[] indexing)
    #pragma unroll
    for (int k = 0; k < 32; ++k) {
        if ((qm >> k) & 1u) {
            float f = __uint_as_float(v[k]);
            int b = (int)(f * scale2);
            b = b > NBINS - 1 ? NBINS - 1 : b;
            atomicAdd(&hist[b], 1u);
        }
    }

    // wave-synchronous exclusive scan: 4 consecutive bins per lane
    {
        uint4* h4 = (uint4*)&hist[lane * 4];
        uint4 a0 = *h4;
        unsigned int c[4] = {a0.x, a0.y, a0.z, a0.w};
        unsigned int loc[4], run = 0;
        #pragma unroll
        for (int k = 0; k < 4; ++k) { loc[k] = run; run += c[k]; }
        unsigned int inc = run;
        #pragma unroll
        for (int d = 1; d < 64; d <<= 1) {
            unsigned int o = (unsigned int)__shfl_up((int)inc, d);
            if (lane >= d) inc += o;
        }
        const unsigned int excl = inc - run;
        uint4 s0 = {excl + loc[0], excl + loc[1], excl + loc[2], excl + loc[3]};
        *h4 = s0;
    }

    // placement: slot = start + arrival order (one atomic per candidate)
    #pragma unroll
    for (int k = 0; k < 32; ++k) {
        if ((qm >> k) & 1u) {
            unsigned int bits = v[k];
            float f = __uint_as_float(bits);
            int b = (int)(f * scale2);
            b = b > NBINS - 1 ? NBINS - 1 : b;
            unsigned int old = atomicAdd(&hist[b], 0x10000u);
            unsigned int slot = (old & 0xFFFFu) + (old >> 16);
            unsigned int idx = (unsigned int)((k >> 2) * 256 + lane * 4 + (k & 3));
            if (slot < (unsigned int)CANDCAP)
                cand[slot] = ((unsigned long long)bits << 32) | idx;
        }
    }

    // rank phase: read slot keys, issue theta gathers early, rank within tiny buckets
    {
        unsigned long long key_s[CANDCAP / 64];
        float th_s[CANDCAP / 64];
        #pragma unroll
        for (int s = 0; s < CANDCAP / 64; ++s) key_s[s] = cand[lane + s * 64];
        #pragma unroll
        for (int s = 0; s < CANDCAP / 64; ++s)
            if (key_s[s] != ~0ULL)
                th_s[s] = theta[(size_t)row * NN + (unsigned int)key_s[s]];
        #pragma unroll
        for (int s = 0; s < CANDCAP / 64; ++s) {
            unsigned long long key = key_s[s];
            if (key != ~0ULL) {
                unsigned int bits = (unsigned int)(key >> 32);
                unsigned int idx  = (unsigned int)key;
                float f = __uint_as_float(bits);
                int b = (int)(f * scale2);
                b = b > NBINS - 1 ? NBINS - 1 : b;
                unsigned int word = hist[b];
                unsigned int start = word & 0xFFFFu;
                unsigned int end = start + (word >> 16);
                if (end > (unsigned int)CANDCAP) end = (unsigned int)CANDCAP;
                unsigned int r = start;
                for (unsigned int j = start; j < end; ++j) r += (cand[j] < key);
                if (r < (unsigned int)LL) {
                    obuf[r] = f;
                    obuf[LL + r] = th_s[s];
                    oidx[r] = (int)idx;
                    if (r == LL - 1) sdm[w] = f;
                }
            }
        }
    }

    // emit (coalesced): xrow[0..127]=dist/dmax, [128..255]=theta, [256..263]=features+pad
    {
        const float rdm = 1.0f / sdm[w];
        float* xrow = xin + (size_t)row * KPAD;
        float4 o = *(float4*)&obuf[lane * 4];
        if (lane < 32) { o.x *= rdm; o.y *= rdm; o.z *= rdm; o.w *= rdm; }
        *(float4*)&xrow[lane * 4] = o;
        if (lane == 0) {
            xrow[256] = f0[row];
            xrow[257] = f1[row];
            #pragma unroll
            for (int z = DIN; z < KPAD; ++z) xrow[z] = 0.0f;
        }
        int2 g = *(int2*)&oidx[lane * 2];
        *(int2*)&gidx[(size_t)row * LL + lane * 2] = g;
    }
}

// ---------------- Kernel C: val = xin @ Wc + bc - dn  (fp32 SGEMM, 128x128 tiles) ----------------
__global__ __launch_bounds__(256) void kC(const float* __restrict__ xin,
                                          const float* __restrict__ Wc,
                                          const float* __restrict__ bc,
                                          float* __restrict__ val) {
    __shared__ __align__(16) float As[8][132];
    __shared__ __align__(16) float Bs[8][128];
    const int t = threadIdx.x;
    const int tr = t >> 4, tc = t & 15;
    const int row0 = blockIdx.x * 128;
    float acc[8][8];
    #pragma unroll
    for (int i = 0; i < 8; ++i)
        #pragma unroll
        for (int j = 0; j < 8; ++j) acc[i][j] = 0.f;

    for (int kc = 0; kc < KPAD; kc += 8) {
        #pragma unroll
        for (int q = 0; q < 4; ++q) {
            int linear = q * 256 + t;
            int m = linear >> 3, k = linear & 7;
            As[k][m] = xin[(size_t)(row0 + m) * KPAD + kc + k];
        }
        #pragma unroll
        for (int q = 0; q < 4; ++q) {
            int linear = q * 256 + t;
            int k = linear >> 7, c = linear & 127;
            Bs[k][c] = Wc[(kc + k) * LL + c];
        }
        __syncthreads();
        #pragma unroll
        for (int k = 0; k < 8; ++k) {
            float a[8], b[8];
            *(float4*)&a[0] = *(const float4*)&As[k][tr * 8];
            *(float4*)&a[4] = *(const float4*)&As[k][tr * 8 + 4];
            *(float4*)&b[0] = *(const float4*)&Bs[k][tc * 8];
            *(float4*)&b[4] = *(const float4*)&Bs[k][tc * 8 + 4];
            #pragma unroll
            for (int i = 0; i < 8; ++i)
                #pragma unroll
                for (int j = 0; j < 8; ++j)
                    acc[i][j] += a[i] * b[j];
        }
        __syncthreads();
    }
    #pragma unroll
    for (int i = 0; i < 8; ++i) {
        int r = row0 + tr * 8 + i;
        #pragma unroll
        for (int j = 0; j < 8; ++j) {
            int c = tc * 8 + j;
            val[(size_t)r * LL + c] = acc[i][j] + bc[c] - xin[(size_t)r * KPAD + c];
        }
    }
}

// ---------------- Kernel D: fill PENALTY row + scatter, stream out ----------------
__global__ __launch_bounds__(256) void kD(const int* __restrict__ gidx,
                                          const float* __restrict__ val,
                                          float* __restrict__ out) {
    __shared__ __align__(16) float rowbuf[NN];
    const int t = threadIdx.x;
    const int row = blockIdx.x;
    for (int i = t; i < NN; i += 256) rowbuf[i] = PENALTY_V;
    __syncthreads();
    if (t < 128) rowbuf[gidx[(size_t)row * LL + t]] = val[(size_t)row * LL + t];
    __syncthreads();
    float4* out4 = (float4*)(out + (size_t)row * NN);
    const float4* rb4 = (const float4*)rowbuf;
    for (int q = t; q < NN / 4; q += 256) out4[q] = rb4[q];
}

extern "C" void kernel_launch(void* const* d_in, const int* in_sizes, int n_in,
                              void* d_out, int out_size, void* d_ws, size_t ws_size,
                              hipStream_t stream) {
    const float* theta = (const float*)d_in[0];
    const float* dist  = (const float*)d_in[1];
    const float* f0    = (const float*)d_in[2];
    const float* f1    = (const float*)d_in[3];
    const float* W1    = (const float*)d_in[4];
    const float* b1    = (const float*)d_in[5];
    const float* W2    = (const float*)d_in[6];
    const float* b2    = (const float*)d_in[7];
    float* out = (float*)d_out;

    char* ws = (char*)d_ws;
    float* Wc   = (float*)ws;                                   // KPAD*128*4 = 135168
    float* bc   = (float*)(ws + 135168);                        // 512
    float* xin  = (float*)(ws + 135680);                        // NROWS*KPAD*4 = 16896000
    int*   gidx = (int*)  (ws + 135680 + 16896000);             // NROWS*128*4 = 8192000
    float* val  = (float*)(ws + 135680 + 16896000 + 8192000);   // NROWS*128*4 = 8192000
    // part aliases val: kA1 writes it, kA2 consumes it, kC later overwrites val.
    float* part = val;                                          // SPLITK*KPAD*128*4 = 2162688 <= 8192000

    kA1<<<33 * SPLITK, 256, 0, stream>>>(W1, b1, W2, part);
    kA2<<<(KPAD * LL) / 256, 256, 0, stream>>>(part, b2, Wc, bc);
    kB<<<NROWS / RPB, 256, 0, stream>>>(dist, theta, f0, f1, xin, gidx);
    kC<<<NROWS / 128, 256, 0, stream>>>(xin, Wc, bc, val);
    kD<<<NROWS, 256, 0, stream>>>(gidx, val, out);
}

// Round 9
// 122.495 us; speedup vs baseline: 1.2358x; 1.1908x over previous
//
#include <hip/hip_runtime.h>
#include <hip/hip_bf16.h>

#define BN 8
#define NN 2000
#define LL 128
#define EE 2048
#define DIN 258
#define KPAD 264
#define NROWS (BN*NN)
#define PENALTY_V 10.0f
#define NBINS 256
#define CANDCAP 256
#define T0 0.092f
#define SPLITK 16
#define ECHUNK (EE/SPLITK)   // 128
#define RPB 4                // rows (waves) per block
#define AWORDS 2392          // per-row arena: 2000 rowbuf | 264 x | 128 oidx

// ---------------- Kernel A1: partial Wc = W1@W2 over one K-slice ----------------
__global__ __launch_bounds__(256) void kA1(const float* __restrict__ W1,
                                           const float* __restrict__ b1,
                                           const float* __restrict__ W2,
                                           float* __restrict__ part) {
    __shared__ float As2[8][64];
    const int t = threadIdx.x;
    const int j = t & 127;
    const int half = t >> 7;              // 0 or 1
    const int rg = blockIdx.x >> 4;       // row group 0..32
    const int ks = blockIdx.x & 15;       // K slice 0..15
    const int k0 = rg * 8;
    const int ebase = ks * ECHUNK;
    float acc[4] = {0.f, 0.f, 0.f, 0.f};
    for (int ec = ebase; ec < ebase + ECHUNK; ec += 64) {
        #pragma unroll
        for (int q = 0; q < 2; ++q) {
            int linear = q * 256 + t;
            int r8 = linear >> 6;
            int e  = linear & 63;
            int k  = k0 + r8;
            float v;
            if (k < DIN)       v = W1[k * EE + ec + e];
            else if (k == DIN) v = b1[ec + e];
            else               v = 0.0f;
            As2[r8][e] = v;
        }
        __syncthreads();
        #pragma unroll 8
        for (int e = 0; e < 64; ++e) {
            float w = W2[(ec + e) * LL + j];
            #pragma unroll
            for (int rr = 0; rr < 4; ++rr)
                acc[rr] += As2[half * 4 + rr][e] * w;
        }
        __syncthreads();
    }
    #pragma unroll
    for (int rr = 0; rr < 4; ++rr) {
        int k = k0 + half * 4 + rr;       // < KPAD always (max 263)
        part[(size_t)ks * (KPAD * LL) + k * LL + j] = acc[rr];
    }
}

// ---------------- Kernel A2: reduce partials -> Wc, bc ----------------
__global__ __launch_bounds__(256) void kA2(const float* __restrict__ part,
                                           const float* __restrict__ b2,
                                           float* __restrict__ Wc,
                                           float* __restrict__ bc) {
    const int i = blockIdx.x * 256 + threadIdx.x;   // 0..KPAD*LL-1
    float s = 0.f;
    #pragma unroll
    for (int q = 0; q < SPLITK; ++q) s += part[(size_t)q * (KPAD * LL) + i];
    const int k = i >> 7;
    const int j = i & 127;
    if (k == DIN)      { bc[j] = s + b2[j]; Wc[i] = 0.f; }
    else if (k > DIN)  { Wc[i] = 0.f; }
    else               { Wc[i] = s; }
}

// ---- Kernel F: FUSED select (R7 machinery) + GEMV + PENALTY scatter + out stream ----
// Per-row arena layout (words): [0..1999] rowbuf (select: hist=0..255, cand=256..767)
//                               [2000..2263] x vector  [2264..2391] oidx
__global__ __launch_bounds__(256) void kF(const float* __restrict__ dist,
                                          const float* __restrict__ theta,
                                          const float* __restrict__ f0,
                                          const float* __restrict__ f1,
                                          const float* __restrict__ Wc,
                                          const float* __restrict__ bc,
                                          float* __restrict__ out) {
    __shared__ __align__(16) unsigned int arena[RPB][AWORDS];   // 38272 B
    const int t = threadIdx.x;
    const int lane = t & 63;
    const int w = t >> 6;
    const int row = blockIdx.x * RPB + w;

    unsigned int* A = arena[w];
    unsigned int* hist = A;                                      // 256 words
    unsigned long long* cand = (unsigned long long*)(A + 256);   // 256 ull
    float* xv = (float*)(A + 2000);                              // 264 floats
    int* oidx = (int*)(A + 2264);                                // 128 ints

    // ---- select phase: wave-local, no barriers (identical logic to R7 kB) ----
    {
        uint4 z4 = {0u, 0u, 0u, 0u};
        *(uint4*)&hist[lane * 4] = z4;
        unsigned long long f1v = ~0ULL;
        #pragma unroll
        for (int q = 0; q < CANDCAP / 64; ++q) cand[lane + q * 64] = f1v;
    }

    unsigned int v[32];
    const int nv = (lane < 52) ? 32 : 28;    // 500 uint4 = 7*64 + 52
    {
        const uint4* drow4 = (const uint4*)(dist + (size_t)row * NN);
        #pragma unroll
        for (int q = 0; q < 8; ++q) {
            int qi = q * 64 + lane;
            if (qi < NN / 4) {
                uint4 a = drow4[qi];
                v[4 * q]     = a.x;
                v[4 * q + 1] = a.y;
                v[4 * q + 2] = a.z;
                v[4 * q + 3] = a.w;
            }
        }
    }

    float T = T0;
    unsigned int qm = 0u;
    #pragma unroll
    for (int k = 0; k < 32; ++k)
        if (k < nv && __uint_as_float(v[k]) <= T) qm |= (1u << k);
    int cnt = __builtin_popcount(qm);
    #pragma unroll
    for (int d = 1; d < 64; d <<= 1) cnt += __shfl_xor(cnt, d);

    if (cnt < LL || cnt > CANDCAP) {
        // cold fallback: exact bisection to land count in [LL, CANDCAP]
        unsigned int lmax = 0u;
        #pragma unroll
        for (int k = 0; k < 32; ++k) if (k < nv) lmax = max(lmax, v[k]);
        #pragma unroll
        for (int d = 1; d < 64; d <<= 1) lmax = max(lmax, (unsigned int)__shfl_xor((int)lmax, d));
        float lo = 0.0f, hi = __uint_as_float(lmax);
        if (cnt < LL) lo = T; else hi = T;
        for (int it = 0; it < 32; ++it) {
            T = 0.5f * (lo + hi);
            unsigned int m = 0u;
            #pragma unroll
            for (int k = 0; k < 32; ++k)
                if (k < nv && __uint_as_float(v[k]) <= T) m |= (1u << k);
            int c = __builtin_popcount(m);
            #pragma unroll
            for (int d = 1; d < 64; d <<= 1) c += __shfl_xor(c, d);
            qm = m;
            if (c >= LL && c <= CANDCAP) break;
            if (c < LL) lo = T; else hi = T;
        }
    }
    const float scale2 = (float)(NBINS - 1) / T;

    // histogram of candidates
    #pragma unroll
    for (int k = 0; k < 32; ++k) {
        if ((qm >> k) & 1u) {
            float f = __uint_as_float(v[k]);
            int b = (int)(f * scale2);
            b = b > NBINS - 1 ? NBINS - 1 : b;
            atomicAdd(&hist[b], 1u);
        }
    }

    // wave-synchronous exclusive scan: 4 consecutive bins per lane
    {
        uint4* h4 = (uint4*)&hist[lane * 4];
        uint4 a0 = *h4;
        unsigned int c[4] = {a0.x, a0.y, a0.z, a0.w};
        unsigned int loc[4], run = 0;
        #pragma unroll
        for (int k = 0; k < 4; ++k) { loc[k] = run; run += c[k]; }
        unsigned int inc = run;
        #pragma unroll
        for (int d = 1; d < 64; d <<= 1) {
            unsigned int o = (unsigned int)__shfl_up((int)inc, d);
            if (lane >= d) inc += o;
        }
        const unsigned int excl = inc - run;
        uint4 s0 = {excl + loc[0], excl + loc[1], excl + loc[2], excl + loc[3]};
        *h4 = s0;
    }

    // placement: slot = start + arrival order (hist low16=start, high16=count)
    #pragma unroll
    for (int k = 0; k < 32; ++k) {
        if ((qm >> k) & 1u) {
            unsigned int bits = v[k];
            float f = __uint_as_float(bits);
            int b = (int)(f * scale2);
            b = b > NBINS - 1 ? NBINS - 1 : b;
            unsigned int old = atomicAdd(&hist[b], 0x10000u);
            unsigned int slot = (old & 0xFFFFu) + (old >> 16);
            unsigned int idx = (unsigned int)((k >> 2) * 256 + lane * 4 + (k & 3));
            if (slot < (unsigned int)CANDCAP)
                cand[slot] = ((unsigned long long)bits << 32) | idx;
        }
    }

    // rank phase: theta gathers issued early; write x (unnormalized) + oidx
    {
        unsigned long long key_s[CANDCAP / 64];
        float th_s[CANDCAP / 64];
        #pragma unroll
        for (int s = 0; s < CANDCAP / 64; ++s) key_s[s] = cand[lane + s * 64];
        #pragma unroll
        for (int s = 0; s < CANDCAP / 64; ++s)
            if (key_s[s] != ~0ULL)
                th_s[s] = theta[(size_t)row * NN + (unsigned int)key_s[s]];
        #pragma unroll
        for (int s = 0; s < CANDCAP / 64; ++s) {
            unsigned long long key = key_s[s];
            if (key != ~0ULL) {
                unsigned int bits = (unsigned int)(key >> 32);
                unsigned int idx  = (unsigned int)key;
                float f = __uint_as_float(bits);
                int b = (int)(f * scale2);
                b = b > NBINS - 1 ? NBINS - 1 : b;
                unsigned int word = hist[b];
                unsigned int start = word & 0xFFFFu;
                unsigned int end = start + (word >> 16);
                if (end > (unsigned int)CANDCAP) end = (unsigned int)CANDCAP;
                unsigned int r = start;
                for (unsigned int j = start; j < end; ++j) r += (cand[j] < key);
                if (r < (unsigned int)LL) {
                    xv[r] = f;
                    xv[LL + r] = th_s[s];
                    oidx[r] = (int)idx;
                }
            }
        }
    }

    // normalize dists in place + features (wave-local; program order guarantees)
    {
        const float rdm = 1.0f / xv[LL - 1];
        xv[lane] *= rdm;
        xv[lane + 64] *= rdm;
        if (lane == 0) {
            xv[256] = f0[row];
            xv[257] = f1[row];
            #pragma unroll
            for (int z = DIN; z < KPAD; ++z) xv[z] = 0.0f;
        }
    }

    __syncthreads();   // barrier1: all rows' x/oidx visible; select structs dead

    // ---- PENALTY fill (block-coop; overwrites hist/cand region, which is dead) ----
    #pragma unroll
    for (int r = 0; r < RPB; ++r) {
        float* rb = (float*)arena[r];
        for (int i = t; i < NN; i += 256) rb[i] = PENALTY_V;
    }

    // ---- GEMV: thread owns col j for rows {2rp, 2rp+1} ----
    const int j = t & 127;
    const int rp = t >> 7;
    const float* x0 = (const float*)(arena[2 * rp] + 2000);
    const float* x1 = (const float*)(arena[2 * rp + 1] + 2000);
    float acc0 = bc[j] - x0[j];
    float acc1 = bc[j] - x1[j];
    #pragma unroll 2
    for (int k = 0; k < KPAD; k += 4) {
        float4 xa = *(const float4*)&x0[k];
        float4 xb = *(const float4*)&x1[k];
        float w0 = Wc[(k + 0) * LL + j];
        float w1 = Wc[(k + 1) * LL + j];
        float w2 = Wc[(k + 2) * LL + j];
        float w3 = Wc[(k + 3) * LL + j];
        acc0 += xa.x * w0; acc1 += xb.x * w0;
        acc0 += xa.y * w1; acc1 += xb.y * w1;
        acc0 += xa.z * w2; acc1 += xb.z * w2;
        acc0 += xa.w * w3; acc1 += xb.w * w3;
    }

    __syncthreads();   // barrier2: PENALTY fill complete before scatter

    // ---- scatter vals into rowbufs ----
    {
        float* rb0 = (float*)arena[2 * rp];
        float* rb1 = (float*)arena[2 * rp + 1];
        const int* oi0 = (const int*)(arena[2 * rp] + 2264);
        const int* oi1 = (const int*)(arena[2 * rp + 1] + 2264);
        rb0[oi0[j]] = acc0;
        rb1[oi1[j]] = acc1;
    }

    __syncthreads();   // barrier3: scatter complete before stream-out

    // ---- stream out: 4 contiguous rows = 2000 float4, coalesced ----
    {
        float4* o4 = (float4*)(out + (size_t)blockIdx.x * RPB * NN);
        for (int i = t; i < RPB * (NN / 4); i += 256) {
            int r = i / (NN / 4);
            int q = i - r * (NN / 4);
            o4[i] = ((const float4*)arena[r])[q];
        }
    }
}

extern "C" void kernel_launch(void* const* d_in, const int* in_sizes, int n_in,
                              void* d_out, int out_size, void* d_ws, size_t ws_size,
                              hipStream_t stream) {
    const float* theta = (const float*)d_in[0];
    const float* dist  = (const float*)d_in[1];
    const float* f0    = (const float*)d_in[2];
    const float* f1    = (const float*)d_in[3];
    const float* W1    = (const float*)d_in[4];
    const float* b1    = (const float*)d_in[5];
    const float* W2    = (const float*)d_in[6];
    const float* b2    = (const float*)d_in[7];
    float* out = (float*)d_out;

    char* ws = (char*)d_ws;
    float* Wc   = (float*)ws;                    // KPAD*128*4 = 135168
    float* bc   = (float*)(ws + 135168);         // 512
    float* part = (float*)(ws + 135680);         // SPLITK*KPAD*128*4 = 2162688

    kA1<<<33 * SPLITK, 256, 0, stream>>>(W1, b1, W2, part);
    kA2<<<(KPAD * LL) / 256, 256, 0, stream>>>(part, b2, Wc, bc);
    kF<<<NROWS / RPB, 256, 0, stream>>>(dist, theta, f0, f1, Wc, bc, out);
}